// Round 1
// baseline (518.864 us; speedup 1.0000x reference)
//
#include <hip/hip_runtime.h>

#define S_LEN 2048
#define D_DIM 2048
#define NHEAD 32
#define NKVH  8
#define HDIM  64
#define NQKV  3072   // 2048 q + 512 k + 512 v

typedef __attribute__((ext_vector_type(4))) float f32x4;
typedef __attribute__((ext_vector_type(8))) short bf16x8;

__device__ __forceinline__ unsigned short f2bf(float x) {
    union { float f; unsigned u; } v; v.f = x;
    unsigned r = v.u + 0x7FFFu + ((v.u >> 16) & 1u);
    return (unsigned short)(r >> 16);
}

// ---------------- h -> bf16 ----------------
__global__ void k_cvt_h(const float* __restrict__ h, unsigned short* __restrict__ hb) {
    int i = (blockIdx.x * 256 + threadIdx.x) * 4;
    float4 v = *(const float4*)(h + i);
    ushort4 o;
    o.x = f2bf(v.x); o.y = f2bf(v.y); o.z = f2bf(v.z); o.w = f2bf(v.w);
    *(ushort4*)(hb + i) = o;
}

// ------------- transpose W [2048][N] f32 -> WT [N][2048] bf16 -------------
__global__ void k_transpose(const float* __restrict__ W, unsigned short* __restrict__ WT, int N) {
    __shared__ unsigned short L[64][65];
    int k0 = blockIdx.x * 64, n0 = blockIdx.y * 64;
    int t = threadIdx.x;
    for (int it = 0; it < 16; ++it) {
        int e = it * 256 + t;
        int r = e >> 6, c = e & 63;                 // r: k, c: n
        L[c][r] = f2bf(W[(size_t)(k0 + r) * N + n0 + c]);
    }
    __syncthreads();
    for (int it = 0; it < 16; ++it) {
        int e = it * 256 + t;
        int n = e >> 6, kk = e & 63;
        WT[(size_t)(n0 + n) * 2048 + k0 + kk] = L[n][kk];
    }
}

// ---------------- adapter: field[s] ----------------
__global__ void k_field(const float* __restrict__ h, const float* __restrict__ Wf,
                        const float* __restrict__ W1, const float* __restrict__ b1,
                        const float* __restrict__ W2, const float* __restrict__ b2,
                        float* __restrict__ field) {
    int s = blockIdx.x;
    int t = threadIdx.x; // 256
    __shared__ float hs[2064];
    __shared__ float hmid[64];
    __shared__ float red[256];
    const float* hr = h + (size_t)s * D_DIM;
    for (int i = t; i < D_DIM; i += 256) hs[i] = hr[i];
    __syncthreads();
    // fiber = h @ Wf  (16 outputs), coalesced over f
    {
        int f = t & 15, part = t >> 4;
        float p = 0.f;
        for (int i = part; i < D_DIM; i += 16) p += hs[i] * Wf[i * 16 + f];
        red[t] = p; __syncthreads();
        if (t < 16) {
            float x = 0.f;
            for (int j = 0; j < 16; ++j) x += red[t + 16 * j];
            hs[D_DIM + t] = x;
        }
        __syncthreads();
    }
    // hmid = gelu(combined @ W1 + b1)  (64 outputs)
    {
        int c = t & 63, part = t >> 6;
        float p = 0.f;
        for (int i = part; i < 2064; i += 4) p += hs[i] * W1[i * 64 + c];
        red[t] = p; __syncthreads();
        if (t < 64) {
            float x = red[t] + red[64 + t] + red[128 + t] + red[192 + t] + b1[t];
            hmid[t] = 0.5f * x * (1.f + erff(x * 0.70710678118654752f));
        }
        __syncthreads();
    }
    // risk -> field
    if (t < 64) {
        float p = hmid[t] * W2[t];
        for (int m = 32; m; m >>= 1) p += __shfl_xor(p, m);
        if (t == 0) field[s] = (float)(1.0 - 0.995) * (p + b2[0]);
    }
}

// ---------------- gate = (field - mean)/(std_ddof1 + 1e-6) ----------------
__global__ void k_gate(const float* __restrict__ field, float* __restrict__ gate) {
    __shared__ float red[256];
    int t = threadIdx.x;
    float s = 0.f;
    for (int i = t; i < S_LEN; i += 256) s += field[i];
    red[t] = s; __syncthreads();
    for (int w = 128; w; w >>= 1) { if (t < w) red[t] += red[t + w]; __syncthreads(); }
    float mean = red[0] / (float)S_LEN;
    __syncthreads();
    float v = 0.f;
    for (int i = t; i < S_LEN; i += 256) { float d = field[i] - mean; v += d * d; }
    red[t] = v; __syncthreads();
    for (int w = 128; w; w >>= 1) { if (t < w) red[t] += red[t + w]; __syncthreads(); }
    float stdv = sqrtf(red[0] / (float)(S_LEN - 1)) + 1e-6f;
    for (int i = t; i < S_LEN; i += 256) gate[i] = (field[i] - mean) / stdv;
}

// ---------------- bf16 MFMA GEMM: C[M][N] = A[M][K] * BT[N][K]^T ----------------
__global__ __launch_bounds__(256) void k_gemm(const unsigned short* __restrict__ A,
                                              const unsigned short* __restrict__ BT,
                                              float* __restrict__ C, int M, int N, int K) {
    __shared__ __align__(16) short As[128 * 32];
    __shared__ __align__(16) short Bs[128 * 32];
    int m0 = blockIdx.y * 128, n0 = blockIdx.x * 128;
    int t = threadIdx.x;
    int wv = t >> 6, ln = t & 63;
    int wr = (wv >> 1) * 64, wc = (wv & 1) * 64;
    int lr = ln & 15, lk = (ln >> 4) * 8;
    f32x4 acc[4][4] = {};
    int sr = t >> 2;           // staging row 0..63
    int sk = (t & 3) * 8;      // staging k 0/8/16/24
    const unsigned short* Ap = A + (size_t)(m0 + sr) * K + sk;
    const unsigned short* Bp = BT + (size_t)(n0 + sr) * K + sk;
    uint4 av0 = *(const uint4*)(Ap);
    uint4 av1 = *(const uint4*)(Ap + (size_t)64 * K);
    uint4 bv0 = *(const uint4*)(Bp);
    uint4 bv1 = *(const uint4*)(Bp + (size_t)64 * K);
    int nk = K / 32;
    for (int kt = 0; kt < nk; ++kt) {
        __syncthreads();
        *(uint4*)&As[sr * 32 + sk] = av0;
        *(uint4*)&As[(64 + sr) * 32 + sk] = av1;
        *(uint4*)&Bs[sr * 32 + sk] = bv0;
        *(uint4*)&Bs[(64 + sr) * 32 + sk] = bv1;
        __syncthreads();
        if (kt + 1 < nk) {
            const unsigned short* Ap2 = Ap + (size_t)(kt + 1) * 32;
            const unsigned short* Bp2 = Bp + (size_t)(kt + 1) * 32;
            av0 = *(const uint4*)(Ap2);
            av1 = *(const uint4*)(Ap2 + (size_t)64 * K);
            bv0 = *(const uint4*)(Bp2);
            bv1 = *(const uint4*)(Bp2 + (size_t)64 * K);
        }
        bf16x8 af[4], bfv[4];
        for (int i = 0; i < 4; ++i) af[i]  = *(const bf16x8*)&As[(wr + i * 16 + lr) * 32 + lk];
        for (int j = 0; j < 4; ++j) bfv[j] = *(const bf16x8*)&Bs[(wc + j * 16 + lr) * 32 + lk];
        for (int i = 0; i < 4; ++i)
            for (int j = 0; j < 4; ++j)
                acc[i][j] = __builtin_amdgcn_mfma_f32_16x16x32_bf16(af[i], bfv[j], acc[i][j], 0, 0, 0);
    }
    int orow = (ln >> 4) * 4;
    for (int i = 0; i < 4; ++i)
        for (int j = 0; j < 4; ++j) {
            float* Cp = C + (size_t)(m0 + wr + i * 16 + orow) * N + n0 + wc + j * 16 + lr;
            for (int r = 0; r < 4; ++r) Cp[(size_t)r * N] = acc[i][j][r];
        }
}

// ---------------- RoPE + layout split (q prescaled by 1/8) ----------------
__global__ void k_rope(const float* __restrict__ qkv, const float* __restrict__ cs,
                       const float* __restrict__ sn,
                       unsigned short* __restrict__ qb, unsigned short* __restrict__ kb,
                       unsigned short* __restrict__ vt) {
    int s = blockIdx.x;
    const float* row = qkv + (size_t)s * NQKV;
    int t = threadIdx.x;
    for (int e = t; e < NQKV; e += 256) {
        int d = e & 63;
        float val = row[e];
        if (e < 2560) {
            float c = cs[s * 64 + d], si = sn[s * 64 + d];
            float partner = (d < 32) ? -row[e + 32] : row[e - 32];
            float out = val * c + partner * si;
            if (e < 2048) {
                int hq = e >> 6;
                qb[((size_t)hq * S_LEN + s) * 64 + d] = f2bf(out * 0.125f);
            } else {
                int hk = (e - 2048) >> 6;
                kb[((size_t)hk * S_LEN + s) * 64 + d] = f2bf(out);
            }
        } else {
            int hv = (e - 2560) >> 6;
            vt[((size_t)hv * 64 + d) * S_LEN + s] = f2bf(val);
        }
    }
}

// ---------------- flash attention: 1 wave = 16 q rows, KV tiles of 32 ----------------
__global__ __launch_bounds__(64) void k_attn(const unsigned short* __restrict__ qb,
                                             const unsigned short* __restrict__ kb,
                                             const unsigned short* __restrict__ vt,
                                             const float* __restrict__ gate,
                                             const float* __restrict__ gs_p,
                                             unsigned short* __restrict__ attnout) {
    int qt = blockIdx.x, h = blockIdx.y;
    int hk = h >> 2;
    int l = threadIdx.x;
    int lr = l & 15, lg = l >> 4;
    float gs = gs_p[0];
    __shared__ __align__(16) short Pl[16 * 32];
    const unsigned short* qrow = qb + ((size_t)h * S_LEN + qt * 16 + lr) * 64;
    bf16x8 aq0 = *(const bf16x8*)(qrow + lg * 8);
    bf16x8 aq1 = *(const bf16x8*)(qrow + 32 + lg * 8);
    float m[4], ls[4]; f32x4 o[4];
    for (int r = 0; r < 4; ++r) { m[r] = -INFINITY; ls[r] = 0.f; }
    for (int j = 0; j < 4; ++j) o[j] = f32x4{0.f, 0.f, 0.f, 0.f};
    int nkt = (qt + 2) >> 1;
    int qpos = qt * 16 + lg * 4;   // + r
    for (int kt = 0; kt < nkt; ++kt) {
        int k0 = kt * 32;
        float pv[2][4];
        float tmax[4];
        for (int r = 0; r < 4; ++r) tmax[r] = -INFINITY;
        for (int c = 0; c < 2; ++c) {
            const unsigned short* krow = kb + ((size_t)hk * S_LEN + k0 + c * 16 + lr) * 64;
            bf16x8 bk0 = *(const bf16x8*)(krow + lg * 8);
            bf16x8 bk1 = *(const bf16x8*)(krow + 32 + lg * 8);
            f32x4 z = {0.f, 0.f, 0.f, 0.f};
            z = __builtin_amdgcn_mfma_f32_16x16x32_bf16(aq0, bk0, z, 0, 0, 0);
            z = __builtin_amdgcn_mfma_f32_16x16x32_bf16(aq1, bk1, z, 0, 0, 0);
            int kpos = k0 + c * 16 + lr;
            float gb = gs * gate[kpos];
            for (int r = 0; r < 4; ++r) {
                float v = z[r] + gb;
                if (kpos > qpos + r) v += -1e9f;
                pv[c][r] = v;
                tmax[r] = fmaxf(tmax[r], v);
            }
        }
        for (int r = 0; r < 4; ++r) {
            float tm = tmax[r];
            tm = fmaxf(tm, __shfl_xor(tm, 1));
            tm = fmaxf(tm, __shfl_xor(tm, 2));
            tm = fmaxf(tm, __shfl_xor(tm, 4));
            tm = fmaxf(tm, __shfl_xor(tm, 8));
            float mn = fmaxf(m[r], tm);
            float scale = expf(m[r] - mn);
            float rs = 0.f;
            for (int c = 0; c < 2; ++c) {
                float p = expf(pv[c][r] - mn);
                pv[c][r] = p;
                rs += p;
            }
            rs += __shfl_xor(rs, 1); rs += __shfl_xor(rs, 2);
            rs += __shfl_xor(rs, 4); rs += __shfl_xor(rs, 8);
            ls[r] = ls[r] * scale + rs;
            m[r] = mn;
            for (int j = 0; j < 4; ++j) o[j][r] *= scale;
        }
        for (int c = 0; c < 2; ++c)
            for (int r = 0; r < 4; ++r)
                Pl[(lg * 4 + r) * 32 + c * 16 + lr] = (short)f2bf(pv[c][r]);
        bf16x8 pa = *(const bf16x8*)&Pl[lr * 32 + lg * 8];
        for (int j = 0; j < 4; ++j) {
            const unsigned short* vrow = vt + ((size_t)hk * 64 + j * 16 + lr) * S_LEN + k0;
            bf16x8 bv = *(const bf16x8*)(vrow + lg * 8);
            o[j] = __builtin_amdgcn_mfma_f32_16x16x32_bf16(pa, bv, o[j], 0, 0, 0);
        }
    }
    for (int r = 0; r < 4; ++r) {
        float inv = 1.f / ls[r];
        unsigned short* orow = attnout + (size_t)(qt * 16 + lg * 4 + r) * 2048 + h * 64;
        for (int j = 0; j < 4; ++j) orow[j * 16 + lr] = f2bf(o[j][r] * inv);
    }
}

extern "C" void kernel_launch(void* const* d_in, const int* in_sizes, int n_in,
                              void* d_out, int out_size, void* d_ws, size_t ws_size,
                              hipStream_t stream) {
    const float* h    = (const float*)d_in[0];
    // d_in[1] = attention_mask (exact causal tril; reproduced analytically)
    const float* cosT = (const float*)d_in[2];
    const float* sinT = (const float*)d_in[3];
    const float* Wf   = (const float*)d_in[4];
    const float* W1   = (const float*)d_in[5];
    const float* b1   = (const float*)d_in[6];
    const float* W2   = (const float*)d_in[7];
    const float* b2   = (const float*)d_in[8];
    const float* gs   = (const float*)d_in[9];
    const float* Wq   = (const float*)d_in[10];
    const float* Wk   = (const float*)d_in[11];
    const float* Wv   = (const float*)d_in[12];
    const float* Wo   = (const float*)d_in[13];
    float* out = (float*)d_out;

    char* ws = (char*)d_ws;
    // layout (bytes)
    unsigned short* hb    = (unsigned short*)(ws);                       // 8 MiB, dead after GEMM1
    unsigned short* wqkv  = (unsigned short*)(ws + 8388608);             // 12 MiB, dead after GEMM1
    unsigned short* wot   = (unsigned short*)(ws + 20971520);            // 8 MiB
    float*          qkv   = (float*)(ws + 29360128);                     // 24 MiB, dead after rope
    float*          field = (float*)(ws + 54525952);                     // 8 KiB
    float*          gate  = (float*)(ws + 54534144);                     // 8 KiB
    // aliases over dead regions:
    unsigned short* qb      = (unsigned short*)(ws + 8388608);           // 8 MiB  (over wqkv)
    unsigned short* kb      = (unsigned short*)(ws + 16777216);          // 2 MiB
    unsigned short* vt      = (unsigned short*)(ws + 18874368);          // 2 MiB
    unsigned short* attnout = (unsigned short*)(ws);                     // 8 MiB  (over hb)

    k_cvt_h<<<dim3(4096), dim3(256), 0, stream>>>(h, hb);
    k_transpose<<<dim3(32, 32), dim3(256), 0, stream>>>(Wq, wqkv, 2048);
    k_transpose<<<dim3(32, 8),  dim3(256), 0, stream>>>(Wk, wqkv + (size_t)2048 * 2048, 512);
    k_transpose<<<dim3(32, 8),  dim3(256), 0, stream>>>(Wv, wqkv + (size_t)2560 * 2048, 512);
    k_transpose<<<dim3(32, 32), dim3(256), 0, stream>>>(Wo, wot, 2048);
    k_field<<<dim3(2048), dim3(256), 0, stream>>>(h, Wf, W1, b1, W2, b2, field);
    k_gate<<<dim3(1), dim3(256), 0, stream>>>(field, gate);
    k_gemm<<<dim3(24, 16), dim3(256), 0, stream>>>(hb, wqkv, qkv, 2048, 3072, 2048);
    k_rope<<<dim3(2048), dim3(256), 0, stream>>>(qkv, cosT, sinT, qb, kb, vt);
    k_attn<<<dim3(128, 32), dim3(64), 0, stream>>>(qb, kb, vt, gate, gs, attnout);
    k_gemm<<<dim3(16, 16), dim3(256), 0, stream>>>(attnout, wot, out, 2048, 2048, 2048);
}